// Round 1
// baseline (2056.696 us; speedup 1.0000x reference)
//
#include <hip/hip_runtime.h>
#include <math.h>

#define NN 50000
#define EE 800000
#define HH 128
#define AHD 64
#define KIT 10
#define NHF (NN * HH)  // 6,400,000 floats per snapshot

__device__ __forceinline__ float gelu_exact(float x) {
  return 0.5f * x * (1.f + erff(x * 0.70710678118654752f));
}

// ---------------- graph preprocessing ----------------
__global__ __launch_bounds__(256) void zero_kernel(float* __restrict__ wsum,
                                                   int* __restrict__ deg, int n) {
  int i = blockIdx.x * 256 + threadIdx.x;
  if (i < n) { wsum[i] = 0.f; deg[i] = 0; }
}

__global__ __launch_bounds__(256) void edge_stats_kernel(const int* __restrict__ ei,
                                                         const float* __restrict__ ew,
                                                         float* __restrict__ wsum,
                                                         int* __restrict__ deg, int e_cnt) {
  int e = blockIdx.x * 256 + threadIdx.x;
  if (e >= e_cnt) return;
  atomicAdd(&wsum[ei[e]], ew[e]);       // sum of outgoing edge weights by source (row)
  atomicAdd(&deg[ei[EE + e]], 1);       // in-degree by destination (col)
}

__global__ __launch_bounds__(1024) void scan_kernel(const int* __restrict__ deg,
                                                    int* __restrict__ row_start,
                                                    int* __restrict__ cursor, int n) {
  __shared__ int buf[1024];
  __shared__ int carry_s;
  int tid = threadIdx.x;
  if (tid == 0) carry_s = 0;
  __syncthreads();
  for (int base = 0; base < n; base += 1024) {
    int i = base + tid;
    int v = (i < n) ? deg[i] : 0;
    buf[tid] = v;
    __syncthreads();
    for (int off = 1; off < 1024; off <<= 1) {
      int t = (tid >= off) ? buf[tid - off] : 0;
      __syncthreads();
      buf[tid] += t;
      __syncthreads();
    }
    int incl = buf[tid];
    int carry = carry_s;
    if (i < n) {
      int ex = carry + incl - v;
      row_start[i] = ex;
      cursor[i] = ex;
    }
    __syncthreads();
    if (tid == 1023) carry_s = carry + incl;
    __syncthreads();
  }
  if (tid == 0) row_start[n] = carry_s;
}

__global__ __launch_bounds__(256) void csr_fill_kernel(const int* __restrict__ ei,
                                                       const float* __restrict__ ew,
                                                       const float* __restrict__ wsum,
                                                       int* __restrict__ cursor,
                                                       int* __restrict__ csr_src,
                                                       float* __restrict__ csr_val, int e_cnt) {
  int e = blockIdx.x * 256 + threadIdx.x;
  if (e >= e_cnt) return;
  int r = ei[e], c = ei[EE + e];
  float ws = wsum[r];
  ws = ws < 1.f ? 1.f : ws;
  float v = 0.9f * ew[e] / ws;            // (1-ALPHA) * enorm folded together
  int pos = atomicAdd(&cursor[c], 1);
  csr_src[pos] = r;
  csr_val[pos] = v;
}

// ---------------- propagation: one wave per node, lane = 2 features ----------------
__global__ __launch_bounds__(256) void prop_kernel(const float* __restrict__ h_cur,
                                                   const float* __restrict__ base,
                                                   const int* __restrict__ row_start,
                                                   const int* __restrict__ csr_src,
                                                   const float* __restrict__ csr_val,
                                                   float* __restrict__ h_next) {
  int node = __builtin_amdgcn_readfirstlane(blockIdx.x * 4 + (threadIdx.x >> 6));
  if (node >= NN) return;
  int lane = threadIdx.x & 63;
  const float2* hc = (const float2*)h_cur;
  float2 b = ((const float2*)base)[node * 64 + lane];
  float accx = 0.1f * b.x, accy = 0.1f * b.y;   // ALPHA * base
  int s = row_start[node], e = row_start[node + 1];
  for (int i = s; i < e; ++i) {
    int src = csr_src[i];      // wave-uniform -> s_load
    float v = csr_val[i];      // wave-uniform -> s_load
    float2 hv = hc[src * 64 + lane];   // coalesced 512B row read
    accx = fmaf(v, hv.x, accx);
    accy = fmaf(v, hv.y, accy);
  }
  float2 o; o.x = accx; o.y = accy;
  ((float2*)h_next)[node * 64 + lane] = o;
}

// ---------------- dense: out[n][j] = act(sum_k X[n][k] * W[j][k] + ...) ----------------
// Block = 256 threads / 4 waves, 128 rows per block (lane -> rows 2l, 2l+1 as float2).
// Wave w computes columns {w, w+4, w+8, ...}; W read via wave-uniform scalar loads.
// ACT: 0 = +bias, 1 = +bias -> BN -> ReLU, 2 = +bias -> GELU(exact)
#define DROWS 128
#define DKC 64
template <int K, int KA, int J, int ACT, bool RESID>
__global__ __launch_bounds__(256) void dense_kernel(
    const float* __restrict__ Xa, const float* __restrict__ Xb,
    const float* __restrict__ W, const float* __restrict__ lb,
    const float* __restrict__ bg, const float* __restrict__ bb,
    const float* __restrict__ bm, const float* __restrict__ bv,
    const float* __restrict__ resid, float* __restrict__ out, int n_rows) {
  static_assert(K % DKC == 0, "K must be multiple of DKC");
  static_assert(J % 4 == 0, "J must be multiple of 4");
  constexpr int JPW = J / 4;   // columns per wave
  __shared__ float xP[DKC][DROWS + 2];
  const int tid = threadIdx.x;
  const int lane = tid & 63;
  const int w = __builtin_amdgcn_readfirstlane(tid >> 6);
  const int r0 = blockIdx.x * DROWS;

  float acc[JPW][2];
#pragma unroll
  for (int i = 0; i < JPW; ++i) { acc[i][0] = 0.f; acc[i][1] = 0.f; }

  for (int kc = 0; kc < K; kc += DKC) {
    __syncthreads();
    // stage chunk transposed: xP[k][r] = X[r0+r][kc+k]
    for (int idx = tid; idx < DROWS * (DKC / 4); idx += 256) {
      int r = idx / (DKC / 4);
      int c4 = (idx % (DKC / 4)) * 4;
      int row = r0 + r;
      int col = kc + c4;
      float4 v = make_float4(0.f, 0.f, 0.f, 0.f);
      if (row < n_rows) {
        if (col < KA) v = *(const float4*)&Xa[(long)row * KA + col];
        else          v = *(const float4*)&Xb[(long)row * (K - KA) + (col - KA)];
      }
      xP[c4 + 0][r] = v.x; xP[c4 + 1][r] = v.y;
      xP[c4 + 2][r] = v.z; xP[c4 + 3][r] = v.w;
    }
    __syncthreads();
    for (int k = 0; k < DKC; ++k) {
      float2 xv = *(const float2*)&xP[k][2 * lane];
      int kk = kc + k;
#pragma unroll
      for (int i = 0; i < JPW; ++i) {
        int j = w + 4 * i;                 // wave-uniform
        float wv = W[(long)j * K + kk];    // scalar load
        acc[i][0] = fmaf(xv.x, wv, acc[i][0]);
        acc[i][1] = fmaf(xv.y, wv, acc[i][1]);
      }
    }
  }
  // epilogue
  int row0 = r0 + 2 * lane, row1 = row0 + 1;
#pragma unroll
  for (int i = 0; i < JPW; ++i) {
    int j = w + 4 * i;
    float a0 = acc[i][0], a1 = acc[i][1];
    float y0, y1;
    if (ACT == 0) {
      float b = lb[j];
      y0 = a0 + b; y1 = a1 + b;
    } else if (ACT == 1) {
      float s = bg[j] * rsqrtf(bv[j] + 1e-5f);
      float sh = (lb[j] - bm[j]) * s + bb[j];
      y0 = fmaxf(fmaf(a0, s, sh), 0.f);
      y1 = fmaxf(fmaf(a1, s, sh), 0.f);
    } else {
      float b = lb[j];
      y0 = gelu_exact(a0 + b); y1 = gelu_exact(a1 + b);
    }
    if (RESID) {
      if (row0 < n_rows) y0 += resid[(long)row0 * J + j];
      if (row1 < n_rows) y1 += resid[(long)row1 * J + j];
    }
    if (row0 < n_rows) out[(long)row0 * J + j] = y0;
    if (row1 < n_rows) out[(long)row1 * J + j] = y1;
  }
}

// ---------------- att2 (64 -> 11) + softmax, one thread per node ----------------
__global__ __launch_bounds__(64) void att2_softmax_kernel(const float* __restrict__ g,
                                                          const float* __restrict__ W2,
                                                          const float* __restrict__ b2,
                                                          float* __restrict__ attw, int n_rows) {
  __shared__ float gl[64][65];
  int r0 = blockIdx.x * 64;
  for (int idx = threadIdx.x; idx < 64 * 16; idx += 64) {
    int r = idx >> 4, c4 = (idx & 15) * 4;
    float4 v = make_float4(0.f, 0.f, 0.f, 0.f);
    if (r0 + r < n_rows) v = *(const float4*)&g[(long)(r0 + r) * 64 + c4];
    gl[r][c4] = v.x; gl[r][c4 + 1] = v.y; gl[r][c4 + 2] = v.z; gl[r][c4 + 3] = v.w;
  }
  __syncthreads();
  int r = threadIdx.x;
  int n = r0 + r;
  if (n >= n_rows) return;
  float a[KIT + 1];
#pragma unroll
  for (int j = 0; j < KIT + 1; ++j) {
    float acc = b2[j];
#pragma unroll
    for (int k = 0; k < 64; ++k) acc = fmaf(gl[r][k], W2[j * 64 + k], acc);
    a[j] = acc;
  }
  float m = a[0];
#pragma unroll
  for (int j = 1; j < KIT + 1; ++j) m = fmaxf(m, a[j]);
  float s = 0.f;
#pragma unroll
  for (int j = 0; j < KIT + 1; ++j) { a[j] = expf(a[j] - m); s += a[j]; }
  float inv = 1.f / s;
#pragma unroll
  for (int j = 0; j < KIT + 1; ++j) attw[n * 16 + j] = a[j] * inv;
}

// ---------------- fuse: fused[n] = sum_k attw[n][k] * xs_k[n] ----------------
__global__ __launch_bounds__(256) void fused_gather_kernel(const float* __restrict__ XS,
                                                           const float* __restrict__ attw,
                                                           float* __restrict__ fused) {
  int idx = blockIdx.x * 256 + threadIdx.x;
  int node = idx >> 6;
  if (node >= NN) return;
  int nu = __builtin_amdgcn_readfirstlane(node);
  int lane = idx & 63;
  float accx = 0.f, accy = 0.f;
#pragma unroll
  for (int k = 0; k <= KIT; ++k) {
    float wk = attw[nu * 16 + k];
    float2 v = *(const float2*)&XS[(long)k * NHF + (long)node * HH + lane * 2];
    accx = fmaf(wk, v.x, accx);
    accy = fmaf(wk, v.y, accy);
  }
  float2 o; o.x = accx; o.y = accy;
  *(float2*)&fused[(long)node * HH + lane * 2] = o;
}

// recompute-path variant: fused (+)= attw[:,k] * h
__global__ __launch_bounds__(256) void fused_accum_kernel(const float* __restrict__ h,
                                                          const float* __restrict__ attw,
                                                          float* __restrict__ fused, int k) {
  int idx = blockIdx.x * 256 + threadIdx.x;
  int node = idx >> 6;
  if (node >= NN) return;
  int nu = __builtin_amdgcn_readfirstlane(node);
  int lane = idx & 63;
  float wk = attw[nu * 16 + k];
  float2 v = *(const float2*)&h[(long)node * HH + lane * 2];
  float2 o;
  if (k == 0) {
    o.x = wk * v.x; o.y = wk * v.y;
  } else {
    float2 f = *(const float2*)&fused[(long)node * HH + lane * 2];
    o.x = fmaf(wk, v.x, f.x); o.y = fmaf(wk, v.y, f.y);
  }
  *(float2*)&fused[(long)node * HH + lane * 2] = o;
}

extern "C" void kernel_launch(void* const* d_in, const int* in_sizes, int n_in,
                              void* d_out, int out_size, void* d_ws, size_t ws_size,
                              hipStream_t stream) {
  (void)in_sizes; (void)n_in; (void)out_size;
  const float* x      = (const float*)d_in[0];
  const int*   ei     = (const int*)d_in[1];
  const float* ew     = (const float*)d_in[2];
  const float* lin1_w = (const float*)d_in[3];
  const float* lin1_b = (const float*)d_in[4];
  const float* bn1_g  = (const float*)d_in[5];
  const float* bn1_b  = (const float*)d_in[6];
  const float* bn1_m  = (const float*)d_in[7];
  const float* bn1_v  = (const float*)d_in[8];
  const float* lin2_w = (const float*)d_in[9];
  const float* lin2_b = (const float*)d_in[10];
  const float* bn2_g  = (const float*)d_in[11];
  const float* bn2_b  = (const float*)d_in[12];
  const float* bn2_m  = (const float*)d_in[13];
  const float* bn2_v  = (const float*)d_in[14];
  const float* att1_w = (const float*)d_in[15];
  const float* att1_b = (const float*)d_in[16];
  const float* att2_w = (const float*)d_in[17];
  const float* att2_b = (const float*)d_in[18];
  const float* head1_w= (const float*)d_in[19];
  const float* head1_b= (const float*)d_in[20];
  const float* bn3_g  = (const float*)d_in[21];
  const float* bn3_b  = (const float*)d_in[22];
  const float* bn3_m  = (const float*)d_in[23];
  const float* bn3_v  = (const float*)d_in[24];
  const float* head2_w= (const float*)d_in[25];
  const float* head2_b= (const float*)d_in[26];
  float* out = (float*)d_out;

  char* p = (char*)d_ws;
  auto alloc = [&](size_t bytes) -> void* {
    void* r = (void*)p;
    p += (bytes + 255) & ~(size_t)255;
    return r;
  };
  float* wsum     = (float*)alloc((size_t)NN * 4);
  int*   deg      = (int*)alloc((size_t)NN * 4);
  int*   row_start= (int*)alloc((size_t)(NN + 1) * 4);
  int*   cursor   = (int*)alloc((size_t)NN * 4);
  int*   csr_src  = (int*)alloc((size_t)EE * 4);
  float* csr_val  = (float*)alloc((size_t)EE * 4);
  float* gbuf     = (float*)alloc((size_t)NN * AHD * 4);
  float* attw     = (float*)alloc((size_t)NN * 16 * 4);
  float* fused    = (float*)alloc((size_t)NN * HH * 4);  // also reused as stem h1
  float* zbuf     = (float*)alloc((size_t)NN * AHD * 4);
  size_t common = (size_t)(p - (char*)d_ws);
  size_t stored_need = common + (size_t)(KIT + 1) * NHF * 4 + 4096;
  bool stored = ws_size >= stored_need;

  const int GE = (EE + 255) / 256;      // edge-parallel grid
  const int GN = (NN + 255) / 256;      // node-parallel grid
  const int GD = (NN + DROWS - 1) / DROWS;  // dense grid (391)
  const int GP = (NN + 3) / 4;          // prop grid (12500)
  const int GF = (NN * 64 + 255) / 256; // per-(node,lane) grid
  const int GA = (NN + 63) / 64;        // att2 grid

  // graph preprocessing (identical work each call)
  zero_kernel<<<GN, 256, 0, stream>>>(wsum, deg, NN);
  edge_stats_kernel<<<GE, 256, 0, stream>>>(ei, ew, wsum, deg, EE);
  scan_kernel<<<1, 1024, 0, stream>>>(deg, row_start, cursor, NN);
  csr_fill_kernel<<<GE, 256, 0, stream>>>(ei, ew, wsum, cursor, csr_src, csr_val, EE);

  if (stored) {
    float* XS = (float*)alloc((size_t)(KIT + 1) * NHF * 4);
    // stem: h1 -> fused buffer, base -> XS slot 0
    dense_kernel<128, 128, 128, 1, false><<<GD, 256, 0, stream>>>(
        x, nullptr, lin1_w, lin1_b, bn1_g, bn1_b, bn1_m, bn1_v, nullptr, fused, NN);
    dense_kernel<128, 128, 128, 1, true><<<GD, 256, 0, stream>>>(
        fused, nullptr, lin2_w, lin2_b, bn2_g, bn2_b, bn2_m, bn2_v, fused, XS, NN);
    // propagation: xs[k] -> xs[k+1]
    for (int k = 0; k < KIT; ++k) {
      prop_kernel<<<GP, 256, 0, stream>>>(XS + (size_t)k * NHF, XS, row_start,
                                          csr_src, csr_val, XS + (size_t)(k + 1) * NHF);
    }
    // attention: ctx = [xs0, xs10]
    dense_kernel<256, 128, 64, 2, false><<<GD, 256, 0, stream>>>(
        XS, XS + (size_t)KIT * NHF, att1_w, att1_b, nullptr, nullptr, nullptr, nullptr,
        nullptr, gbuf, NN);
    att2_softmax_kernel<<<GA, 64, 0, stream>>>(gbuf, att2_w, att2_b, attw, NN);
    fused_gather_kernel<<<GF, 256, 0, stream>>>(XS, attw, fused);
  } else {
    float* base = (float*)alloc((size_t)NHF * 4);
    float* hA   = (float*)alloc((size_t)NHF * 4);
    float* hB   = (float*)alloc((size_t)NHF * 4);
    dense_kernel<128, 128, 128, 1, false><<<GD, 256, 0, stream>>>(
        x, nullptr, lin1_w, lin1_b, bn1_g, bn1_b, bn1_m, bn1_v, nullptr, fused, NN);
    dense_kernel<128, 128, 128, 1, true><<<GD, 256, 0, stream>>>(
        fused, nullptr, lin2_w, lin2_b, bn2_g, bn2_b, bn2_m, bn2_v, fused, base, NN);
    // pass 1: get xs10
    const float* cur = base;
    for (int k = 1; k <= KIT; ++k) {
      float* nxt = (k & 1) ? hA : hB;
      prop_kernel<<<GP, 256, 0, stream>>>(cur, base, row_start, csr_src, csr_val, nxt);
      cur = nxt;
    }
    dense_kernel<256, 128, 64, 2, false><<<GD, 256, 0, stream>>>(
        base, cur, att1_w, att1_b, nullptr, nullptr, nullptr, nullptr, nullptr, gbuf, NN);
    att2_softmax_kernel<<<GA, 64, 0, stream>>>(gbuf, att2_w, att2_b, attw, NN);
    // pass 2: re-propagate, accumulate fused on the fly
    fused_accum_kernel<<<GF, 256, 0, stream>>>(base, attw, fused, 0);
    cur = base;
    for (int k = 1; k <= KIT; ++k) {
      float* nxt = (k & 1) ? hA : hB;
      prop_kernel<<<GP, 256, 0, stream>>>(cur, base, row_start, csr_src, csr_val, nxt);
      fused_accum_kernel<<<GF, 256, 0, stream>>>(nxt, attw, fused, k);
      cur = nxt;
    }
  }

  // heads
  dense_kernel<128, 128, 64, 1, false><<<GD, 256, 0, stream>>>(
      fused, nullptr, head1_w, head1_b, bn3_g, bn3_b, bn3_m, bn3_v, nullptr, zbuf, NN);
  dense_kernel<64, 64, 40, 0, false><<<GD, 256, 0, stream>>>(
      zbuf, nullptr, head2_w, head2_b, nullptr, nullptr, nullptr, nullptr, nullptr, out, NN);
}

// Round 2
// 1971.293 us; speedup vs baseline: 1.0433x; 1.0433x over previous
//
#include <hip/hip_runtime.h>
#include <math.h>

#define NN 50000
#define EE 800000
#define HH 128
#define AHD 64
#define KIT 10
#define NHF (NN * HH)  // 6,400,000 floats per snapshot

__device__ __forceinline__ float gelu_exact(float x) {
  return 0.5f * x * (1.f + erff(x * 0.70710678118654752f));
}

// ---------------- graph preprocessing ----------------
__global__ __launch_bounds__(256) void zero_kernel(float* __restrict__ wsum,
                                                   int* __restrict__ deg, int n) {
  int i = blockIdx.x * 256 + threadIdx.x;
  if (i < n) { wsum[i] = 0.f; deg[i] = 0; }
}

__global__ __launch_bounds__(256) void edge_stats_kernel(const int* __restrict__ ei,
                                                         const float* __restrict__ ew,
                                                         float* __restrict__ wsum,
                                                         int* __restrict__ deg, int e_cnt) {
  int e = blockIdx.x * 256 + threadIdx.x;
  if (e >= e_cnt) return;
  atomicAdd(&wsum[ei[e]], ew[e]);       // sum of outgoing edge weights by source (row)
  atomicAdd(&deg[ei[EE + e]], 1);       // in-degree by destination (col)
}

// chunked single-block scan: each thread owns a contiguous chunk, one 1024-wide
// block scan of partial sums, then local writeback. 2 passes over deg total.
__global__ __launch_bounds__(1024) void scan_kernel(const int* __restrict__ deg,
                                                    int* __restrict__ row_start,
                                                    int* __restrict__ cursor, int n) {
  __shared__ int psum[1024];
  int tid = threadIdx.x;
  const int CH = (n + 1023) / 1024;
  int begin = tid * CH;
  int end = begin + CH < n ? begin + CH : n;
  int s = 0;
  for (int i = begin; i < end; ++i) s += deg[i];
  psum[tid] = s;
  __syncthreads();
  for (int off = 1; off < 1024; off <<= 1) {
    int t = (tid >= off) ? psum[tid - off] : 0;
    __syncthreads();
    psum[tid] += t;
    __syncthreads();
  }
  int ex = psum[tid] - s;  // exclusive prefix of this chunk
  for (int i = begin; i < end; ++i) {
    row_start[i] = ex;
    cursor[i] = ex;
    ex += deg[i];
  }
  if (tid == 1023) row_start[n] = psum[1023];
}

__global__ __launch_bounds__(256) void csr_fill_kernel(const int* __restrict__ ei,
                                                       const float* __restrict__ ew,
                                                       const float* __restrict__ wsum,
                                                       int* __restrict__ cursor,
                                                       int2* __restrict__ csr, int e_cnt) {
  int e = blockIdx.x * 256 + threadIdx.x;
  if (e >= e_cnt) return;
  int r = ei[e], c = ei[EE + e];
  float ws = wsum[r];
  ws = ws < 1.f ? 1.f : ws;
  float v = 0.9f * ew[e] / ws;            // (1-ALPHA) * enorm folded together
  int pos = atomicAdd(&cursor[c], 1);
  csr[pos] = make_int2(r, __float_as_int(v));
}

// ---------------- propagation: one wave per node, lane = 2 features ----------------
// Edge list walked with wave-uniform s_load_dwordx2 (packed int2 {src, valbits});
// unrolled x4 so 4 coalesced 512B row-gathers are in flight per iteration.
__global__ __launch_bounds__(256, 8) void prop_kernel(const float* __restrict__ h_cur,
                                                      const float* __restrict__ base,
                                                      const int* __restrict__ row_start,
                                                      const int2* __restrict__ csr,
                                                      float* __restrict__ h_next) {
  int node = __builtin_amdgcn_readfirstlane(blockIdx.x * 4 + (threadIdx.x >> 6));
  if (node >= NN) return;
  int lane = threadIdx.x & 63;
  const float2* hc = (const float2*)h_cur;
  float2 b = ((const float2*)base)[node * 64 + lane];
  float ax = 0.1f * b.x, ay = 0.1f * b.y;   // ALPHA * base
  float bx = 0.f, by = 0.f;
  int s = row_start[node], e = row_start[node + 1];
  int i = s;
  for (; i + 4 <= e; i += 4) {
    int2 e0 = csr[i], e1 = csr[i + 1], e2 = csr[i + 2], e3 = csr[i + 3];
    float2 h0 = hc[e0.x * 64 + lane];
    float2 h1 = hc[e1.x * 64 + lane];
    float2 h2 = hc[e2.x * 64 + lane];
    float2 h3 = hc[e3.x * 64 + lane];
    float v0 = __int_as_float(e0.y), v1 = __int_as_float(e1.y);
    float v2 = __int_as_float(e2.y), v3 = __int_as_float(e3.y);
    ax = fmaf(v0, h0.x, ax); ay = fmaf(v0, h0.y, ay);
    bx = fmaf(v1, h1.x, bx); by = fmaf(v1, h1.y, by);
    ax = fmaf(v2, h2.x, ax); ay = fmaf(v2, h2.y, ay);
    bx = fmaf(v3, h3.x, bx); by = fmaf(v3, h3.y, by);
  }
  for (; i < e; ++i) {
    int2 e0 = csr[i];
    float v0 = __int_as_float(e0.y);
    float2 h0 = hc[e0.x * 64 + lane];
    ax = fmaf(v0, h0.x, ax); ay = fmaf(v0, h0.y, ay);
  }
  float2 o; o.x = ax + bx; o.y = ay + by;
  ((float2*)h_next)[node * 64 + lane] = o;
}

// ---------------- dense: out[n][j] = act(sum_k X[n][k] * W[j][k] + ...) ----------------
// Block = 256 threads / 4 waves, 64 rows per block, lane l -> row r0+l.
// Wave w computes columns {w, w+4, w+8, ...} -> max 32 accumulators/thread (no spill).
// X chunk staged row-major in LDS with +4 pad (16B-aligned b128 reads, conflict-free);
// W fetched via wave-uniform s_load_dwordx4.
#define DROWS 64
#define DKC 64
template <int K, int KA, int J, int ACT, bool RESID>
__global__ __launch_bounds__(256, 4) void dense_kernel(
    const float* __restrict__ Xa, const float* __restrict__ Xb,
    const float* __restrict__ W, const float* __restrict__ lb,
    const float* __restrict__ bg, const float* __restrict__ bb,
    const float* __restrict__ bm, const float* __restrict__ bv,
    const float* __restrict__ resid, float* __restrict__ out, int n_rows) {
  static_assert(K % DKC == 0, "K must be multiple of DKC");
  static_assert(J % 4 == 0, "J must be multiple of 4");
  constexpr int JPW = J / 4;   // columns per wave (<= 32)
  __shared__ float xP[DROWS][DKC + 4];
  const int tid = threadIdx.x;
  const int lane = tid & 63;
  const int w = __builtin_amdgcn_readfirstlane(tid >> 6);
  const int r0 = blockIdx.x * DROWS;

  float acc[JPW];
#pragma unroll
  for (int i = 0; i < JPW; ++i) acc[i] = 0.f;

  for (int kc = 0; kc < K; kc += DKC) {
    __syncthreads();
    // stage chunk: xP[r][k] = X[r0+r][kc+k], b128 stores
    for (int idx = tid; idx < DROWS * (DKC / 4); idx += 256) {
      int r = idx >> 4;             // DKC/4 == 16
      int c4 = (idx & 15) * 4;
      int row = r0 + r;
      int col = kc + c4;
      float4 v = make_float4(0.f, 0.f, 0.f, 0.f);
      if (row < n_rows) {
        if (col < KA) v = *(const float4*)&Xa[(long)row * KA + col];
        else          v = *(const float4*)&Xb[(long)row * (K - KA) + (col - KA)];
      }
      *(float4*)&xP[r][c4] = v;
    }
    __syncthreads();
    for (int k4 = 0; k4 < DKC; k4 += 4) {
      float4 xv = *(const float4*)&xP[lane][k4];   // ds_read_b128
#pragma unroll
      for (int i = 0; i < JPW; ++i) {
        int j = w + 4 * i;                              // wave-uniform
        float4 wv = *(const float4*)&W[(long)j * K + kc + k4];  // s_load_dwordx4
        acc[i] = fmaf(xv.x, wv.x, acc[i]);
        acc[i] = fmaf(xv.y, wv.y, acc[i]);
        acc[i] = fmaf(xv.z, wv.z, acc[i]);
        acc[i] = fmaf(xv.w, wv.w, acc[i]);
      }
    }
  }
  // epilogue
  int row = r0 + lane;
  if (row < n_rows) {
#pragma unroll
    for (int i = 0; i < JPW; ++i) {
      int j = w + 4 * i;
      float a = acc[i];
      float y;
      if (ACT == 0) {
        y = a + lb[j];
      } else if (ACT == 1) {
        float s = bg[j] * rsqrtf(bv[j] + 1e-5f);
        float sh = (lb[j] - bm[j]) * s + bb[j];
        y = fmaxf(fmaf(a, s, sh), 0.f);
      } else {
        y = gelu_exact(a + lb[j]);
      }
      if (RESID) y += resid[(long)row * J + j];
      out[(long)row * J + j] = y;
    }
  }
}

// ---------------- att2 (64 -> 11) + softmax, one thread per node ----------------
__global__ __launch_bounds__(64) void att2_softmax_kernel(const float* __restrict__ g,
                                                          const float* __restrict__ W2,
                                                          const float* __restrict__ b2,
                                                          float* __restrict__ attw, int n_rows) {
  __shared__ float gl[64][65];
  int r0 = blockIdx.x * 64;
  for (int idx = threadIdx.x; idx < 64 * 16; idx += 64) {
    int r = idx >> 4, c4 = (idx & 15) * 4;
    float4 v = make_float4(0.f, 0.f, 0.f, 0.f);
    if (r0 + r < n_rows) v = *(const float4*)&g[(long)(r0 + r) * 64 + c4];
    gl[r][c4] = v.x; gl[r][c4 + 1] = v.y; gl[r][c4 + 2] = v.z; gl[r][c4 + 3] = v.w;
  }
  __syncthreads();
  int r = threadIdx.x;
  int n = r0 + r;
  if (n >= n_rows) return;
  float a[KIT + 1];
#pragma unroll
  for (int j = 0; j < KIT + 1; ++j) {
    float acc = b2[j];
#pragma unroll
    for (int k = 0; k < 64; ++k) acc = fmaf(gl[r][k], W2[j * 64 + k], acc);
    a[j] = acc;
  }
  float m = a[0];
#pragma unroll
  for (int j = 1; j < KIT + 1; ++j) m = fmaxf(m, a[j]);
  float s = 0.f;
#pragma unroll
  for (int j = 0; j < KIT + 1; ++j) { a[j] = expf(a[j] - m); s += a[j]; }
  float inv = 1.f / s;
#pragma unroll
  for (int j = 0; j < KIT + 1; ++j) attw[n * 16 + j] = a[j] * inv;
}

// ---------------- fuse: fused[n] = sum_k attw[n][k] * xs_k[n] ----------------
__global__ __launch_bounds__(256) void fused_gather_kernel(const float* __restrict__ XS,
                                                           const float* __restrict__ attw,
                                                           float* __restrict__ fused) {
  int idx = blockIdx.x * 256 + threadIdx.x;
  int node = idx >> 6;
  if (node >= NN) return;
  int nu = __builtin_amdgcn_readfirstlane(node);
  int lane = idx & 63;
  float accx = 0.f, accy = 0.f;
#pragma unroll
  for (int k = 0; k <= KIT; ++k) {
    float wk = attw[nu * 16 + k];
    float2 v = *(const float2*)&XS[(long)k * NHF + (long)node * HH + lane * 2];
    accx = fmaf(wk, v.x, accx);
    accy = fmaf(wk, v.y, accy);
  }
  float2 o; o.x = accx; o.y = accy;
  *(float2*)&fused[(long)node * HH + lane * 2] = o;
}

// recompute-path variant: fused (+)= attw[:,k] * h
__global__ __launch_bounds__(256) void fused_accum_kernel(const float* __restrict__ h,
                                                          const float* __restrict__ attw,
                                                          float* __restrict__ fused, int k) {
  int idx = blockIdx.x * 256 + threadIdx.x;
  int node = idx >> 6;
  if (node >= NN) return;
  int nu = __builtin_amdgcn_readfirstlane(node);
  int lane = idx & 63;
  float wk = attw[nu * 16 + k];
  float2 v = *(const float2*)&h[(long)node * HH + lane * 2];
  float2 o;
  if (k == 0) {
    o.x = wk * v.x; o.y = wk * v.y;
  } else {
    float2 f = *(const float2*)&fused[(long)node * HH + lane * 2];
    o.x = fmaf(wk, v.x, f.x); o.y = fmaf(wk, v.y, f.y);
  }
  *(float2*)&fused[(long)node * HH + lane * 2] = o;
}

extern "C" void kernel_launch(void* const* d_in, const int* in_sizes, int n_in,
                              void* d_out, int out_size, void* d_ws, size_t ws_size,
                              hipStream_t stream) {
  (void)in_sizes; (void)n_in; (void)out_size;
  const float* x      = (const float*)d_in[0];
  const int*   ei     = (const int*)d_in[1];
  const float* ew     = (const float*)d_in[2];
  const float* lin1_w = (const float*)d_in[3];
  const float* lin1_b = (const float*)d_in[4];
  const float* bn1_g  = (const float*)d_in[5];
  const float* bn1_b  = (const float*)d_in[6];
  const float* bn1_m  = (const float*)d_in[7];
  const float* bn1_v  = (const float*)d_in[8];
  const float* lin2_w = (const float*)d_in[9];
  const float* lin2_b = (const float*)d_in[10];
  const float* bn2_g  = (const float*)d_in[11];
  const float* bn2_b  = (const float*)d_in[12];
  const float* bn2_m  = (const float*)d_in[13];
  const float* bn2_v  = (const float*)d_in[14];
  const float* att1_w = (const float*)d_in[15];
  const float* att1_b = (const float*)d_in[16];
  const float* att2_w = (const float*)d_in[17];
  const float* att2_b = (const float*)d_in[18];
  const float* head1_w= (const float*)d_in[19];
  const float* head1_b= (const float*)d_in[20];
  const float* bn3_g  = (const float*)d_in[21];
  const float* bn3_b  = (const float*)d_in[22];
  const float* bn3_m  = (const float*)d_in[23];
  const float* bn3_v  = (const float*)d_in[24];
  const float* head2_w= (const float*)d_in[25];
  const float* head2_b= (const float*)d_in[26];
  float* out = (float*)d_out;

  char* p = (char*)d_ws;
  auto alloc = [&](size_t bytes) -> void* {
    void* r = (void*)p;
    p += (bytes + 255) & ~(size_t)255;
    return r;
  };
  float* wsum     = (float*)alloc((size_t)NN * 4);
  int*   deg      = (int*)alloc((size_t)NN * 4);
  int*   row_start= (int*)alloc((size_t)(NN + 1) * 4);
  int*   cursor   = (int*)alloc((size_t)NN * 4);
  int2*  csr      = (int2*)alloc((size_t)EE * 8);
  float* gbuf     = (float*)alloc((size_t)NN * AHD * 4);
  float* attw     = (float*)alloc((size_t)NN * 16 * 4);
  float* fused    = (float*)alloc((size_t)NN * HH * 4);  // also reused as stem h1
  float* zbuf     = (float*)alloc((size_t)NN * AHD * 4);
  size_t common = (size_t)(p - (char*)d_ws);
  size_t stored_need = common + (size_t)(KIT + 1) * NHF * 4 + 4096;
  bool stored = ws_size >= stored_need;

  const int GE = (EE + 255) / 256;      // edge-parallel grid
  const int GN = (NN + 255) / 256;      // node-parallel grid
  const int GD = (NN + DROWS - 1) / DROWS;  // dense grid (782)
  const int GP = (NN + 3) / 4;          // prop grid (12500)
  const int GF = (NN * 64 + 255) / 256; // per-(node,lane) grid
  const int GA = (NN + 63) / 64;        // att2 grid

  // graph preprocessing (identical work each call)
  zero_kernel<<<GN, 256, 0, stream>>>(wsum, deg, NN);
  edge_stats_kernel<<<GE, 256, 0, stream>>>(ei, ew, wsum, deg, EE);
  scan_kernel<<<1, 1024, 0, stream>>>(deg, row_start, cursor, NN);
  csr_fill_kernel<<<GE, 256, 0, stream>>>(ei, ew, wsum, cursor, csr, EE);

  if (stored) {
    float* XS = (float*)alloc((size_t)(KIT + 1) * NHF * 4);
    // stem: h1 -> fused buffer, base -> XS slot 0
    dense_kernel<128, 128, 128, 1, false><<<GD, 256, 0, stream>>>(
        x, nullptr, lin1_w, lin1_b, bn1_g, bn1_b, bn1_m, bn1_v, nullptr, fused, NN);
    dense_kernel<128, 128, 128, 1, true><<<GD, 256, 0, stream>>>(
        fused, nullptr, lin2_w, lin2_b, bn2_g, bn2_b, bn2_m, bn2_v, fused, XS, NN);
    // propagation: xs[k] -> xs[k+1]
    for (int k = 0; k < KIT; ++k) {
      prop_kernel<<<GP, 256, 0, stream>>>(XS + (size_t)k * NHF, XS, row_start,
                                          csr, XS + (size_t)(k + 1) * NHF);
    }
    // attention: ctx = [xs0, xs10]
    dense_kernel<256, 128, 64, 2, false><<<GD, 256, 0, stream>>>(
        XS, XS + (size_t)KIT * NHF, att1_w, att1_b, nullptr, nullptr, nullptr, nullptr,
        nullptr, gbuf, NN);
    att2_softmax_kernel<<<GA, 64, 0, stream>>>(gbuf, att2_w, att2_b, attw, NN);
    fused_gather_kernel<<<GF, 256, 0, stream>>>(XS, attw, fused);
  } else {
    float* base = (float*)alloc((size_t)NHF * 4);
    float* hA   = (float*)alloc((size_t)NHF * 4);
    float* hB   = (float*)alloc((size_t)NHF * 4);
    dense_kernel<128, 128, 128, 1, false><<<GD, 256, 0, stream>>>(
        x, nullptr, lin1_w, lin1_b, bn1_g, bn1_b, bn1_m, bn1_v, nullptr, fused, NN);
    dense_kernel<128, 128, 128, 1, true><<<GD, 256, 0, stream>>>(
        fused, nullptr, lin2_w, lin2_b, bn2_g, bn2_b, bn2_m, bn2_v, fused, base, NN);
    // pass 1: get xs10
    const float* cur = base;
    for (int k = 1; k <= KIT; ++k) {
      float* nxt = (k & 1) ? hA : hB;
      prop_kernel<<<GP, 256, 0, stream>>>(cur, base, row_start, csr, nxt);
      cur = nxt;
    }
    dense_kernel<256, 128, 64, 2, false><<<GD, 256, 0, stream>>>(
        base, cur, att1_w, att1_b, nullptr, nullptr, nullptr, nullptr, nullptr, gbuf, NN);
    att2_softmax_kernel<<<GA, 64, 0, stream>>>(gbuf, att2_w, att2_b, attw, NN);
    // pass 2: re-propagate, accumulate fused on the fly
    fused_accum_kernel<<<GF, 256, 0, stream>>>(base, attw, fused, 0);
    cur = base;
    for (int k = 1; k <= KIT; ++k) {
      float* nxt = (k & 1) ? hA : hB;
      prop_kernel<<<GP, 256, 0, stream>>>(cur, base, row_start, csr, nxt);
      fused_accum_kernel<<<GF, 256, 0, stream>>>(nxt, attw, fused, k);
      cur = nxt;
    }
  }

  // heads
  dense_kernel<128, 128, 64, 1, false><<<GD, 256, 0, stream>>>(
      fused, nullptr, head1_w, head1_b, bn3_g, bn3_b, bn3_m, bn3_v, nullptr, zbuf, NN);
  dense_kernel<64, 64, 40, 0, false><<<GD, 256, 0, stream>>>(
      zbuf, nullptr, head2_w, head2_b, nullptr, nullptr, nullptr, nullptr, nullptr, out, NN);
}